// Round 17
// baseline (129.097 us; speedup 1.0000x reference)
//
#include <hip/hip_runtime.h>
#include <hip/hip_bf16.h>
#include <cstdint>

// MultiHeadAttention fused pipeline for MI355X (gfx950).
// cvt(fp32->bf16) -> QKV GEMM (dbuf; Q pre-scaled) -> V transpose -> zero(acc)
// -> flash attention (causal, 32x32 MFMA, in-reg P, KV-CHUNKED across blocks:
//    additive no-max softmax partials, f32 atomic combine for split tiles)
// -> combine(normalize) -> out-proj GEMM (dbuf).

#define DEV __device__ __forceinline__

#define VT_STRIDE 2048  // V^T row stride in elems
#define QSCALE 0.1803368801f  // 0.125 * log2(e); folded into Q at QKV epilogue

using bf16x8 = __attribute__((ext_vector_type(8))) short;
using f32x4  = __attribute__((ext_vector_type(4))) float;
using f32x16 = __attribute__((ext_vector_type(16))) float;
using u32x4  = __attribute__((ext_vector_type(4))) unsigned;

DEV unsigned short f2bf(float f) {
  unsigned u = __builtin_bit_cast(unsigned, f);
  u = (u + 0x7fffu + ((u >> 16) & 1u)) >> 16;  // RNE
  return (unsigned short)u;
}

DEV float exp2_hw(float x) {  // exactly v_exp_f32: 2^x; exp2(-inf)=0
  float r;
  asm("v_exp_f32 %0, %1" : "=v"(r) : "v"(x));
  return r;
}

typedef __attribute__((address_space(1))) unsigned int as1_uint;
typedef __attribute__((address_space(3))) unsigned int as3_uint;

DEV void gload_lds16(const void* g, void* l) {
  __builtin_amdgcn_global_load_lds(
      (as1_uint*)(uintptr_t)g,
      (as3_uint*)(unsigned int)(uintptr_t)l,
      16, 0, 0);
}

// fused fp32->bf16 convert for x | W_qkv | W_out (one launch).
#define N4_X  (4096 * 1024 / 4)
#define N4_WQ (3072 * 1024 / 4)
#define N4_WO (1024 * 1024 / 4)
__global__ __launch_bounds__(256) void cvt_all_k(const float* __restrict__ x,
                                                 const float* __restrict__ wq,
                                                 const float* __restrict__ wo,
                                                 unsigned short* __restrict__ xb,
                                                 unsigned short* __restrict__ wqb,
                                                 unsigned short* __restrict__ wob) {
  int i = blockIdx.x * 256 + threadIdx.x;
  const float* in; unsigned short* out;
  if (i < N4_X)                { in = x;  out = xb; }
  else if (i < N4_X + N4_WQ)   { i -= N4_X;  in = wq; out = wqb; }
  else                         { i -= N4_X + N4_WQ; in = wo; out = wob; }
  float4 v = reinterpret_cast<const float4*>(in)[i];
  ushort4 o;
  o.x = f2bf(v.x); o.y = f2bf(v.y); o.z = f2bf(v.z); o.w = f2bf(v.w);
  reinterpret_cast<ushort4*>(out)[i] = o;
}

// zero the f32 partial accumulators (Oacc 12MB + lacc 192KB = 798720 float4)
__global__ __launch_bounds__(256) void zero_k(float4* __restrict__ p) {
  const float4 z = {0.f, 0.f, 0.f, 0.f};
  p[blockIdx.x * 256 + threadIdx.x] = z;
}

// normalize split-tile partials (rows 512..2047 of every bh) into AO bf16.
__global__ __launch_bounds__(256) void combine_k(const float* __restrict__ Oacc,
                                                 const float* __restrict__ lacc,
                                                 unsigned short* __restrict__ AO) {
  const int i = blockIdx.x * 256 + threadIdx.x;   // 32*1536*16 = 786432
  const int d4 = i & 15;
  const int rem = i >> 4;                          // bh*1536 + row
  const int row = rem % 1536;
  const int bh = rem / 1536;
  const float inv = 1.0f / lacc[rem];
  float4 v = reinterpret_cast<const float4*>(Oacc)[i];
  const int b = bh >> 4, h = bh & 15;
  ushort4 u;
  u.x = f2bf(v.x * inv); u.y = f2bf(v.y * inv);
  u.z = f2bf(v.z * inv); u.w = f2bf(v.w * inv);
  *(ushort4*)(AO + ((size_t)(b * 2048 + 512 + row)) * 1024 + h * 64 + d4 * 4) = u;
}

// C[M,N] = A[M,K](bf16) * W[N,K](bf16)^T + bias.
// MODE 0: Cout fp32 [M,N].  MODE 1: scatter to Q/K/V [bh,s,d] bf16; Q scaled.
template <int MODE, int N, int K>
__global__ __launch_bounds__(256) void gemm_bt(const unsigned short* __restrict__ A,
                                               const unsigned short* __restrict__ W,
                                               const float* __restrict__ bias,
                                               float* __restrict__ Cout,
                                               unsigned short* __restrict__ Qp,
                                               unsigned short* __restrict__ Kp,
                                               unsigned short* __restrict__ Vp) {
  __shared__ unsigned short As[2][128 * 64];
  __shared__ unsigned short Bs[2][128 * 64];
  const int tid = threadIdx.x;
  const int m0 = blockIdx.x * 128;
  const int n0 = blockIdx.y * 128;
  const int w = tid >> 6, lane = tid & 63, g = lane >> 4, lr = lane & 15;
  const int wr = w >> 1, wc = w & 1;
  const int xr = (lr & 7) << 4;

  f32x4 acc[4][4];
#pragma unroll
  for (int i = 0; i < 4; ++i)
#pragma unroll
    for (int j = 0; j < 4; ++j)
#pragma unroll
      for (int r = 0; r < 4; ++r) acc[i][j][r] = 0.f;

#define GSTAGE(buf, kt)                                                                     \
  do {                                                                                      \
    _Pragma("unroll")                                                                       \
    for (int it = 0; it < 4; ++it) {                                                        \
      const int c = it * 256 + tid;                                                         \
      const int row = c >> 3;                                                               \
      const int colb = ((c & 7) * 16) ^ ((row & 7) << 4);                                   \
      gload_lds16((const char*)(A + (size_t)(m0 + row) * K + (kt)) + colb,                  \
                  (char*)As[buf] + c * 16);                                                 \
      gload_lds16((const char*)(W + (size_t)(n0 + row) * K + (kt)) + colb,                  \
                  (char*)Bs[buf] + c * 16);                                                 \
    }                                                                                       \
  } while (0)

  GSTAGE(0, 0);
  int cur = 0;
  const int nsteps = K / 64;
  for (int step = 0; step < nsteps; ++step) {
    if (step + 1 < nsteps) {
      GSTAGE(cur ^ 1, (step + 1) * 64);
      asm volatile("s_waitcnt vmcnt(8)" ::: "memory");
    } else {
      asm volatile("s_waitcnt vmcnt(0)" ::: "memory");
    }
    __builtin_amdgcn_s_barrier();
    __builtin_amdgcn_sched_barrier(0);

    const char* AsC = (const char*)As[cur];
    const char* BsC = (const char*)Bs[cur];
    __builtin_amdgcn_s_setprio(1);
#pragma unroll
    for (int ks = 0; ks < 2; ++ks) {
      bf16x8 af[4], bf[4];
#pragma unroll
      for (int mi = 0; mi < 4; ++mi)
        af[mi] = *(const bf16x8*)(AsC +
                   ((((wr * 64 + mi * 16 + lr) * 128) + ks * 64 + g * 16) ^ xr));
#pragma unroll
      for (int ni = 0; ni < 4; ++ni)
        bf[ni] = *(const bf16x8*)(BsC +
                   ((((wc * 64 + ni * 16 + lr) * 128) + ks * 64 + g * 16) ^ xr));
#pragma unroll
      for (int mi = 0; mi < 4; ++mi)
#pragma unroll
        for (int ni = 0; ni < 4; ++ni)
          acc[mi][ni] = __builtin_amdgcn_mfma_f32_16x16x32_bf16(af[mi], bf[ni], acc[mi][ni], 0, 0, 0);
    }
    __builtin_amdgcn_s_setprio(0);

    asm volatile("" ::: "memory");
    __builtin_amdgcn_s_barrier();
    __builtin_amdgcn_sched_barrier(0);
    cur ^= 1;
  }
#undef GSTAGE

  if (MODE == 0) {
#pragma unroll
    for (int ni = 0; ni < 4; ++ni) {
      const int col = n0 + wc * 64 + ni * 16 + lr;
      const float bv = bias[col];
#pragma unroll
      for (int mi = 0; mi < 4; ++mi)
#pragma unroll
        for (int r = 0; r < 4; ++r) {
          const int row = m0 + wr * 64 + mi * 16 + g * 4 + r;
          Cout[(size_t)row * N + col] = acc[mi][ni][r] + bv;
        }
    }
  } else {
#pragma unroll
    for (int ni = 0; ni < 4; ++ni) {
      const int col = n0 + wc * 64 + ni * 16 + lr;
      const float bv = bias[col];
      const int which = col >> 10;
      const int h = (col >> 6) & 15;
      const int d = col & 63;
      unsigned short* P = which == 0 ? Qp : which == 1 ? Kp : Vp;
      const float scl = which == 0 ? QSCALE : 1.0f;
#pragma unroll
      for (int mi = 0; mi < 4; ++mi)
#pragma unroll
        for (int r = 0; r < 4; ++r) {
          const int row = m0 + wr * 64 + mi * 16 + g * 4 + r;
          const int b = row >> 11, s = row & 2047;
          P[(((size_t)(b * 16 + h) * 2048 + s) << 6) + d] = f2bf((acc[mi][ni][r] + bv) * scl);
        }
    }
  }
}

// V [bh, s, d] -> V^T [bh, d, s].  64x64 tiles through swizzled LDS.
__global__ __launch_bounds__(256) void transpose_v_k(const unsigned short* __restrict__ V,
                                                     unsigned short* __restrict__ Vt) {
  const int bh = blockIdx.x;
  const int st = blockIdx.y;
  const int tid = threadIdx.x;
  __shared__ unsigned short T[64 * 64];
  const unsigned short* src = V + ((size_t)bh * 2048 + st * 64) * 64;

#pragma unroll
  for (int it = 0; it < 2; ++it) {
    const int c = it * 256 + tid;
    const int L = c * 16;
    const int S = L ^ (((L >> 10) & 7) << 4);
    gload_lds16((const char*)src + S, (char*)T + L);
  }
  __syncthreads();

#pragma unroll
  for (int it = 0; it < 2; ++it) {
    const int c = it * 256 + tid;
    const int d = c >> 3;
    const int s_off = (c & 7) * 8;
    const int xg = (c & 7) << 4;
    bf16x8 pk;
#pragma unroll
    for (int j = 0; j < 8; ++j)
      pk[j] = *(const short*)((const char*)T + (((s_off + j) * 128 + d * 2) ^ xg));
    *(bf16x8*)(Vt + (size_t)(bh * 64 + d) * VT_STRIDE + st * 64 + s_off) = pk;
  }
}

// Flash attention, causal, KV-CHUNKED. grid (bh=32, y=80), 128 threads = 2 waves.
// y enumerates (qt, chunk) pairs, qt DESCENDING (long chunks dispatch first):
// tile qt has (qt>>3)+1 chunks of <=8 kv-blocks (512 keys). Longest serial
// chain drops 32 -> 8 iterations; 2560 blocks @ 16KB LDS -> ~10 blocks/CU
// co-resident (TLP hides the single-buffer __syncthreads drains, m114 regime).
// No-max softmax partials are ADDITIVE: qt<8 (single chunk) writes AO direct;
// qt>=8 chunks atomicAdd f32 (Oacc rows 512.., lacc) combined by combine_k.
// 32x32x16 MFMA, swapped QK^T, in-reg P via cvt_pk + shfl_xor(32).
__global__ __launch_bounds__(128) void attn_fwd(const unsigned short* __restrict__ Q,
                                                const unsigned short* __restrict__ Kg,
                                                const unsigned short* __restrict__ Vt,
                                                unsigned short* __restrict__ AO,
                                                float* __restrict__ Oacc,
                                                float* __restrict__ lacc) {
  const int bh = blockIdx.x;            // b*16 + h
  int yy = blockIdx.y, qt = 0, c = 0;
  for (int qq = 31; qq >= 0; --qq) {    // scalar, 32 iters max, once
    const int n = (qq >> 3) + 1;
    if (yy < n) { qt = qq; c = yy; break; }
    yy -= n;
  }
  const int tid = threadIdx.x;
  const int w = tid >> 6, lane = tid & 63;
  const int l31 = lane & 31, hi = lane >> 5;
  const int xr = (lane & 7) << 4;
  const unsigned short* Qp = Q  + (size_t)bh * 2048 * 64;
  const unsigned short* Kp = Kg + (size_t)bh * 2048 * 64;
  const unsigned short* Vp = Vt + (size_t)bh * 64 * VT_STRIDE;
  const int b = bh >> 4, h = bh & 15;

  __shared__ unsigned short Ks[64 * 64];  // 8 KB (single buffer)
  __shared__ unsigned short Vs[64 * 64];  // 8 KB

#define STAGE(kvb)                                                                          \
  do {                                                                                      \
    _Pragma("unroll")                                                                       \
    for (int it = 0; it < 4; ++it) {                                                        \
      const int Lc = (it * 128 + tid) * 16;                                                 \
      const int Gc = Lc ^ (((Lc >> 7) & 7) << 4);                                           \
      gload_lds16((const char*)Kp + (size_t)(kvb) * 128 + Gc, (char*)Ks + Lc);              \
      gload_lds16((const char*)Vp + (size_t)(Gc >> 7) * (VT_STRIDE * 2) +                   \
                      (size_t)(kvb) * 2 + (Gc & 127), (char*)Vs + Lc);                      \
    }                                                                                       \
  } while (0)

  const int kv0 = c * 8;                       // first kv block of this chunk
  const int nbl = min(8, qt + 1 - kv0);        // kv blocks in this chunk
  const bool split = (qt >= 8);
  const int qrow0 = qt * 64 + w * 32;          // this wave's 32 q-rows

  // Q as B-fragments: B[k=d][col=q=l31]
  bf16x8 qf[4];
#pragma unroll
  for (int ds = 0; ds < 4; ++ds)
    qf[ds] = *(const bf16x8*)(Qp + (size_t)(qrow0 + l31) * 64 + ds * 16 + hi * 8);

  f32x16 o0, o1;       // O[q rows][d 0-31], [d 32-63]
#pragma unroll
  for (int r = 0; r < 16; ++r) { o0[r] = 0.f; o1[r] = 0.f; }
  float lp = 0.f;

  for (int tl = 0; tl < nbl; ++tl) {
    const int tglob = kv0 + tl;
    STAGE(tglob * 64);
    __syncthreads();   // K/V staged (vmcnt drained; TLP across ~10 blocks hides)

    // ---- QK^T SWAPPED (32x32x16): D[col=q=l31, row=key (reg,hi) layout] ----
    f32x16 s0, s1;
#pragma unroll
    for (int r = 0; r < 16; ++r) { s0[r] = 0.f; s1[r] = 0.f; }
    __builtin_amdgcn_s_setprio(1);
#pragma unroll
    for (int ds = 0; ds < 4; ++ds) {
      bf16x8 k0 = *(const bf16x8*)((const char*)Ks + ((l31 * 128 + ds * 32 + hi * 16) ^ xr));
      bf16x8 k1 = *(const bf16x8*)((const char*)Ks + (((32 + l31) * 128 + ds * 32 + hi * 16) ^ xr));
      s0 = __builtin_amdgcn_mfma_f32_32x32x16_bf16(k0, qf[ds], s0, 0, 0, 0);
      s1 = __builtin_amdgcn_mfma_f32_32x32x16_bf16(k1, qf[ds], s1, 0, 0, 0);
    }
    __builtin_amdgcn_s_setprio(0);

    // ---- causal mask (only the diagonal kv block; it's in the last chunk) ----
    if (tglob == qt) {
      const int thr = w * 32 + l31;
#pragma unroll
      for (int reg = 0; reg < 16; ++reg) {
        const int koff = (reg & 3) + 8 * (reg >> 2) + 4 * hi;
        if (koff > thr)      s0[reg] = -INFINITY;
        if (koff + 32 > thr) s1[reg] = -INFINITY;
      }
    }

    // ---- softmax: p = v_exp(s) (Q pre-scaled); per-lane partial sum ----
#pragma unroll
    for (int reg = 0; reg < 16; ++reg) {
      float a0 = exp2_hw(s0[reg]);
      float a1 = exp2_hw(s1[reg]);
      s0[reg] = a0; s1[reg] = a1;
      lp += a0 + a1;
    }

    // ---- pack P into PV A-frags (in-register; cvt_pk + shfl_xor(32)) ----
    bf16x8 pa[4];
#pragma unroll
    for (int kb = 0; kb < 2; ++kb) {
      unsigned wv[8], tv[8];
#pragma unroll
      for (int j = 0; j < 8; ++j) {
        float e0 = kb ? s1[2 * j] : s0[2 * j];
        float e1 = kb ? s1[2 * j + 1] : s0[2 * j + 1];
        asm("v_cvt_pk_bf16_f32 %0, %1, %2" : "=v"(wv[j]) : "v"(e0), "v"(e1));
      }
#pragma unroll
      for (int j = 0; j < 8; ++j) tv[j] = (unsigned)__shfl_xor((int)wv[j], 32);
      u32x4 ua, ub;
      ua[0] = hi ? tv[2] : wv[0]; ua[1] = hi ? tv[3] : wv[1];
      ua[2] = hi ? wv[2] : tv[0]; ua[3] = hi ? wv[3] : tv[1];
      ub[0] = hi ? tv[6] : wv[4]; ub[1] = hi ? tv[7] : wv[5];
      ub[2] = hi ? wv[6] : tv[4]; ub[3] = hi ? wv[7] : tv[5];
      pa[kb * 2]     = __builtin_bit_cast(bf16x8, ua);
      pa[kb * 2 + 1] = __builtin_bit_cast(bf16x8, ub);
    }

    // ---- PV (32x32x16): O[q][d] += P[q][k] V[k][d] ----
    __builtin_amdgcn_s_setprio(1);
#pragma unroll
    for (int ks = 0; ks < 4; ++ks) {
      bf16x8 v0 = *(const bf16x8*)((const char*)Vs + ((l31 * 128 + ks * 32 + hi * 16) ^ xr));
      bf16x8 v1 = *(const bf16x8*)((const char*)Vs + (((32 + l31) * 128 + ks * 32 + hi * 16) ^ xr));
      o0 = __builtin_amdgcn_mfma_f32_32x32x16_bf16(pa[ks], v0, o0, 0, 0, 0);
      o1 = __builtin_amdgcn_mfma_f32_32x32x16_bf16(pa[ks], v1, o1, 0, 0, 0);
    }
    __builtin_amdgcn_s_setprio(0);

    __syncthreads();   // both waves done reading Ks/Vs before next STAGE
  }

  // ---- finalize ----
  lp += __shfl_xor(lp, 32);   // full (chunk-partial) row sum for q = l31

  if (!split) {
    const float inv = 1.0f / lp;
#pragma unroll
    for (int reg = 0; reg < 16; ++reg) {
      const int qoff = (reg & 3) + 8 * (reg >> 2) + 4 * hi;
      const float li = __shfl(inv, qoff);
      const int row = qrow0 + qoff;
      AO[(size_t)(b * 2048 + row) * 1024 + h * 64 + l31]      = f2bf(o0[reg] * li);
      AO[(size_t)(b * 2048 + row) * 1024 + h * 64 + 32 + l31] = f2bf(o1[reg] * li);
    }
  } else {
    if (hi == 0)
      atomicAdd(&lacc[bh * 1536 + qrow0 - 512 + l31], lp);
#pragma unroll
    for (int reg = 0; reg < 16; ++reg) {
      const int qoff = (reg & 3) + 8 * (reg >> 2) + 4 * hi;
      const size_t base = ((size_t)bh * 1536 + (qrow0 + qoff - 512)) * 64;
      atomicAdd(&Oacc[base + l31],      o0[reg]);
      atomicAdd(&Oacc[base + 32 + l31], o1[reg]);
    }
  }
#undef STAGE
}

extern "C" void kernel_launch(void* const* d_in, const int* in_sizes, int n_in,
                              void* d_out, int out_size, void* d_ws, size_t ws_size,
                              hipStream_t stream) {
  const float* x     = (const float*)d_in[0];
  const float* W_qkv = (const float*)d_in[1];
  const float* b_qkv = (const float*)d_in[2];
  const float* W_out = (const float*)d_in[3];
  const float* b_out = (const float*)d_in[4];
  float* out = (float*)d_out;

  // workspace layout (48 MB, fully rewritten every call):
  //  [0,8)   xb (cvt out; dead after QKV gemm)    -> Oacc f32 12MB spans [0,12)
  //  [8,14)  wqb (dead after QKV gemm)            -> (Oacc tail + lacc at 12MB)
  //  [14,22) Vb natural V (dead after transpose)  -> AOb bf16 8MB
  //  [22,24) wob (live until out-proj)
  //  [24,32) Qb   [32,40) Kb   [40,48) Vtb
  char* ws = (char*)d_ws;
  unsigned short* xb  = (unsigned short*)(ws);
  float*          Oacc= (float*)(ws);                               // 12 MB
  unsigned short* wqb = (unsigned short*)(ws + ((size_t)8 << 20));
  float*          lacc= (float*)(ws + ((size_t)12 << 20));          // 192 KB
  unsigned short* Vb  = (unsigned short*)(ws + ((size_t)14 << 20)); // 8 MB
  unsigned short* AOb = (unsigned short*)(ws + ((size_t)14 << 20)); // reuse
  unsigned short* wob = (unsigned short*)(ws + ((size_t)22 << 20)); // 2 MB
  unsigned short* Qb  = (unsigned short*)(ws + ((size_t)24 << 20));
  unsigned short* Kb  = (unsigned short*)(ws + ((size_t)32 << 20));
  unsigned short* Vtb = (unsigned short*)(ws + ((size_t)40 << 20));

  cvt_all_k<<<(N4_X + N4_WQ + N4_WO) / 256, 256, 0, stream>>>(x, W_qkv, W_out, xb, wqb, wob);

  gemm_bt<1, 3072, 1024><<<dim3(32, 24), 256, 0, stream>>>(xb, wqb, b_qkv, nullptr, Qb, Kb, Vb);
  transpose_v_k<<<dim3(32, 32), 256, 0, stream>>>(Vb, Vtb);
  zero_k<<<798720 / 256, 256, 0, stream>>>((float4*)Oacc);  // Oacc 12MB + lacc 192KB
  attn_fwd<<<dim3(32, 80), 128, 0, stream>>>(Qb, Kb, Vtb, AOb, Oacc, lacc);
  combine_k<<<786432 / 256, 256, 0, stream>>>(Oacc, lacc, AOb);
  gemm_bt<0, 1024, 1024><<<dim3(32, 8), 256, 0, stream>>>(AOb, wob, b_out, out, nullptr, nullptr, nullptr);
}